// Round 1
// baseline (40.941 us; speedup 1.0000x reference)
//
#include <hip/hip_runtime.h>
#include <math.h>

#define BB 64
#define TT 2048
#define QD 1024
#define AD 256

__device__ __forceinline__ float tanh_fast(float x) {
    // exact algebra: tanh(x) = 1 - 2/(e^{2x}+1); __expf/__fdividef are few-ulp
    float e = __expf(2.0f * x);
    return 1.0f - __fdividef(2.0f, e + 1.0f);
}

// pq[b][a] = sum_q query[b][q] * Wq[a][q]; one wave per (b,a)
__global__ __launch_bounds__(256) void pq_kernel(const float* __restrict__ query,
                                                 const float* __restrict__ Wq,
                                                 float* __restrict__ pq) {
    int w    = (blockIdx.x * blockDim.x + threadIdx.x) >> 6;  // global wave id
    int lane = threadIdx.x & 63;
    int b = w >> 8;      // / AD
    int a = w & (AD - 1);
    const float4* qrow = (const float4*)(query + (size_t)b * QD);
    const float4* wrow = (const float4*)(Wq + (size_t)a * QD);
    float acc = 0.f;
    #pragma unroll
    for (int i = 0; i < QD / 4 / 64; ++i) {  // 4 iterations
        float4 q4 = qrow[lane + i * 64];
        float4 w4 = wrow[lane + i * 64];
        acc += q4.x * w4.x + q4.y * w4.y + q4.z * w4.z + q4.w * w4.w;
    }
    #pragma unroll
    for (int off = 32; off > 0; off >>= 1)
        acc += __shfl_down(acc, off, 64);
    if (lane == 0) pq[w] = acc;
}

// energies[b][t] = mask * sum_a tanh(pq[b][a] + esp[b][t][a]) * v[a]
// one wave per (b,t); lane i holds a = 4i..4i+3 (float4) -> wave reads 1KB row
__global__ __launch_bounds__(256) void energy_kernel(const float* __restrict__ esp,
                                                     const float* __restrict__ pq,
                                                     const float* __restrict__ v,
                                                     const int* __restrict__ chars,
                                                     float* __restrict__ energies) {
    int w    = (blockIdx.x * blockDim.x + threadIdx.x) >> 6;  // = b*T + t
    int lane = threadIdx.x & 63;
    int b = w >> 11;  // / TT
    const float4* erow = (const float4*)(esp + (size_t)w * AD);
    const float4* prow = (const float4*)(pq + (size_t)b * AD);
    const float4* vrow = (const float4*)v;
    float4 e4 = erow[lane];
    float4 p4 = prow[lane];
    float4 v4 = vrow[lane];
    float s = tanh_fast(p4.x + e4.x) * v4.x
            + tanh_fast(p4.y + e4.y) * v4.y
            + tanh_fast(p4.z + e4.z) * v4.z
            + tanh_fast(p4.w + e4.w) * v4.w;
    #pragma unroll
    for (int off = 32; off > 0; off >>= 1)
        s += __shfl_down(s, off, 64);
    if (lane == 0) {
        energies[w] = (chars[w] != 0) ? s : 0.0f;
    }
}

// in-place masked softmax over each row of length T; one block (256 thr) per b
__global__ __launch_bounds__(256) void softmax_kernel(float* __restrict__ io) {
    __shared__ float red[4];
    int tid  = threadIdx.x;
    int wave = tid >> 6, lane = tid & 63;
    float* row = io + (size_t)blockIdx.x * TT;
    float vals[8];
    float m = -INFINITY;
    #pragma unroll
    for (int i = 0; i < 8; ++i) {
        vals[i] = row[i * 256 + tid];
        m = fmaxf(m, vals[i]);
    }
    #pragma unroll
    for (int off = 32; off > 0; off >>= 1)
        m = fmaxf(m, __shfl_xor(m, off, 64));
    if (lane == 0) red[wave] = m;
    __syncthreads();
    m = fmaxf(fmaxf(red[0], red[1]), fmaxf(red[2], red[3]));
    __syncthreads();
    float s = 0.f;
    #pragma unroll
    for (int i = 0; i < 8; ++i) {
        vals[i] = __expf(vals[i] - m);
        s += vals[i];
    }
    #pragma unroll
    for (int off = 32; off > 0; off >>= 1)
        s += __shfl_xor(s, off, 64);
    if (lane == 0) red[wave] = s;
    __syncthreads();
    s = red[0] + red[1] + red[2] + red[3];
    float inv = __fdividef(1.0f, s);
    #pragma unroll
    for (int i = 0; i < 8; ++i)
        row[i * 256 + tid] = vals[i] * inv;
}

extern "C" void kernel_launch(void* const* d_in, const int* in_sizes, int n_in,
                              void* d_out, int out_size, void* d_ws, size_t ws_size,
                              hipStream_t stream) {
    const float* esp   = (const float*)d_in[0];  // (B,T,AD)
    const float* query = (const float*)d_in[1];  // (B,QD)
    const int*   chars = (const int*)d_in[2];    // (B,T)
    // d_in[3] = t (unused by the reference math)
    const float* Wq    = (const float*)d_in[4];  // (AD,QD)
    const float* v     = (const float*)d_in[5];  // (AD,)
    float* out = (float*)d_out;                  // (B,T)
    float* pq  = (float*)d_ws;                   // B*AD floats = 64KB scratch

    pq_kernel<<<(BB * AD) / 4, 256, 0, stream>>>(query, Wq, pq);
    energy_kernel<<<(BB * TT) / 4, 256, 0, stream>>>(esp, pq, v, chars, out);
    softmax_kernel<<<BB, 256, 0, stream>>>(out);
}

// Round 2
// 34.781 us; speedup vs baseline: 1.1771x; 1.1771x over previous
//
#include <hip/hip_runtime.h>
#include <math.h>

#define BB 64
#define TT 2048
#define QD 1024
#define AD 256

__device__ __forceinline__ float tanh_fast(float x) {
    // exact algebra: tanh(x) = 1 - 2/(e^{2x}+1); __expf/__fdividef are few-ulp
    float e = __expf(2.0f * x);
    return 1.0f - __fdividef(2.0f, e + 1.0f);
}

// pq[b][a] = sum_q query[b][q] * Wq[a][q]
// one wave per (4 b's x 4 a's) tile: q rows live in registers, Wq read once
// per 4 b's -> L2 traffic ~32MB instead of ~144MB.
__global__ __launch_bounds__(256) void pq_kernel(const float* __restrict__ query,
                                                 const float* __restrict__ Wq,
                                                 float* __restrict__ pq) {
    int wg   = (blockIdx.x * blockDim.x + threadIdx.x) >> 6;  // 0..1023
    int lane = threadIdx.x & 63;
    int b0 = (wg >> 6) * 4;   // 16 b-groups
    int a0 = (wg & 63) * 4;   // 64 a-groups
    float4 qr[4][4];
    #pragma unroll
    for (int i = 0; i < 4; ++i) {
        const float4* qrow = (const float4*)(query + (size_t)(b0 + i) * QD);
        #pragma unroll
        for (int k = 0; k < 4; ++k) qr[i][k] = qrow[lane + k * 64];
    }
    float acc[4][4];
    #pragma unroll
    for (int j = 0; j < 4; ++j) {
        const float4* wrow = (const float4*)(Wq + (size_t)(a0 + j) * QD);
        float4 w4[4];
        #pragma unroll
        for (int k = 0; k < 4; ++k) w4[k] = wrow[lane + k * 64];
        #pragma unroll
        for (int i = 0; i < 4; ++i) {
            float a = 0.f;
            #pragma unroll
            for (int k = 0; k < 4; ++k)
                a += qr[i][k].x * w4[k].x + qr[i][k].y * w4[k].y
                   + qr[i][k].z * w4[k].z + qr[i][k].w * w4[k].w;
            acc[i][j] = a;
        }
    }
    #pragma unroll
    for (int off = 32; off > 0; off >>= 1)
        #pragma unroll
        for (int i = 0; i < 4; ++i)
            #pragma unroll
            for (int j = 0; j < 4; ++j)
                acc[i][j] += __shfl_down(acc[i][j], off, 64);
    if (lane == 0) {
        #pragma unroll
        for (int i = 0; i < 4; ++i) {
            float4 r = make_float4(acc[i][0], acc[i][1], acc[i][2], acc[i][3]);
            ((float4*)(pq + (size_t)(b0 + i) * AD))[a0 >> 2] = r;
        }
    }
}

// energies[b][t] = mask * sum_a tanh(pq[b][a] + esp[b][t][a]) * v[a]
// one wave per 4 consecutive rows (same b): 4 loads in flight, 4 interleaved
// reduction chains, float4 store.
__global__ __launch_bounds__(256) void energy_kernel(const float* __restrict__ esp,
                                                     const float* __restrict__ pq,
                                                     const float* __restrict__ v,
                                                     const int* __restrict__ chars,
                                                     float* __restrict__ energies) {
    int wg   = (blockIdx.x * blockDim.x + threadIdx.x) >> 6;
    int lane = threadIdx.x & 63;
    int w0 = wg * 4;          // first row (b*T + t), 4-aligned -> same b
    int b  = w0 >> 11;        // / TT
    const float4* erow = (const float4*)(esp + (size_t)w0 * AD);
    float4 e4[4];
    #pragma unroll
    for (int j = 0; j < 4; ++j) e4[j] = erow[j * 64 + lane];
    float4 p4 = ((const float4*)(pq + (size_t)b * AD))[lane];
    float4 v4 = ((const float4*)v)[lane];
    float s[4];
    #pragma unroll
    for (int j = 0; j < 4; ++j) {
        s[j] = tanh_fast(p4.x + e4[j].x) * v4.x
             + tanh_fast(p4.y + e4[j].y) * v4.y
             + tanh_fast(p4.z + e4[j].z) * v4.z
             + tanh_fast(p4.w + e4[j].w) * v4.w;
    }
    #pragma unroll
    for (int off = 32; off > 0; off >>= 1)
        #pragma unroll
        for (int j = 0; j < 4; ++j)
            s[j] += __shfl_down(s[j], off, 64);
    if (lane == 0) {
        int4 cc = *(const int4*)(chars + w0);
        float4 r;
        r.x = cc.x ? s[0] : 0.f;
        r.y = cc.y ? s[1] : 0.f;
        r.z = cc.z ? s[2] : 0.f;
        r.w = cc.w ? s[3] : 0.f;
        *(float4*)(energies + w0) = r;
    }
}

// in-place masked softmax over each row of length T; one block (1024 thr) per b
__global__ __launch_bounds__(1024) void softmax_kernel(float* __restrict__ io) {
    __shared__ float red[16];
    int tid  = threadIdx.x;
    int wave = tid >> 6, lane = tid & 63;
    float* row = io + (size_t)blockIdx.x * TT;
    float2 vv = ((float2*)row)[tid];
    float m = fmaxf(vv.x, vv.y);
    #pragma unroll
    for (int off = 32; off > 0; off >>= 1)
        m = fmaxf(m, __shfl_xor(m, off, 64));
    if (lane == 0) red[wave] = m;
    __syncthreads();
    float mm = red[0];
    #pragma unroll
    for (int i = 1; i < 16; ++i) mm = fmaxf(mm, red[i]);
    __syncthreads();
    float e0 = __expf(vv.x - mm);
    float e1 = __expf(vv.y - mm);
    float s = e0 + e1;
    #pragma unroll
    for (int off = 32; off > 0; off >>= 1)
        s += __shfl_xor(s, off, 64);
    if (lane == 0) red[wave] = s;
    __syncthreads();
    float ss = 0.f;
    #pragma unroll
    for (int i = 0; i < 16; ++i) ss += red[i];
    float inv = __fdividef(1.0f, ss);
    ((float2*)row)[tid] = make_float2(e0 * inv, e1 * inv);
}

extern "C" void kernel_launch(void* const* d_in, const int* in_sizes, int n_in,
                              void* d_out, int out_size, void* d_ws, size_t ws_size,
                              hipStream_t stream) {
    const float* esp   = (const float*)d_in[0];  // (B,T,AD)
    const float* query = (const float*)d_in[1];  // (B,QD)
    const int*   chars = (const int*)d_in[2];    // (B,T)
    // d_in[3] = t (unused by the reference math)
    const float* Wq    = (const float*)d_in[4];  // (AD,QD)
    const float* v     = (const float*)d_in[5];  // (AD,)
    float* out = (float*)d_out;                  // (B,T)
    float* pq  = (float*)d_ws;                   // B*AD floats = 64KB scratch

    pq_kernel<<<256, 256, 0, stream>>>(query, Wq, pq);
    energy_kernel<<<(BB * TT) / 16, 256, 0, stream>>>(esp, pq, v, chars, out);
    softmax_kernel<<<BB, 1024, 0, stream>>>(out);
}